// Round 6
// baseline (170.369 us; speedup 1.0000x reference)
//
#include <hip/hip_runtime.h>
#include <stdint.h>

static constexpr int Kdim  = 1024;    // L
static constexpr int Ncols = 512;    // OUT

typedef __attribute__((ext_vector_type(8)))  short bf16x8;
typedef __attribute__((ext_vector_type(16))) float f32x16;

__device__ __forceinline__ unsigned short f2bf(float f) {
  unsigned u = __builtin_bit_cast(unsigned, f);
  u += 0x7FFFu + ((u >> 16) & 1u);          // RNE
  return (unsigned short)(u >> 16);
}
__device__ __forceinline__ unsigned f2bf2(float lo, float hi) {
  unsigned ul = __builtin_bit_cast(unsigned, lo);
  unsigned uh = __builtin_bit_cast(unsigned, hi);
  ul += 0x7FFFu + ((ul >> 16) & 1u);
  uh += 0x7FFFu + ((uh >> 16) & 1u);
  return (ul >> 16) | (uh & 0xFFFF0000u);
}

// async global->LDS, 16B per lane; LDS dest = wave-uniform base + lane*16
__device__ __forceinline__ void gl2lds16(const void* g, void* l) {
  __builtin_amdgcn_global_load_lds(
      (const __attribute__((address_space(1))) void*)g,
      (__attribute__((address_space(3))) void*)l, 16, 0, 0);
}

// ---------------------------------------------------------------------------
// Kernel 1 (tiny): Wt[n][k] = bf16(0.5*(W_in[k][n]+W_out[k][n])+W_root[k][n])
// ---------------------------------------------------------------------------
__global__ __launch_bounds__(256) void combine_w(
    const float* __restrict__ Win, const float* __restrict__ Wout,
    const float* __restrict__ Wroot, unsigned short* __restrict__ Wt)
{
  __shared__ unsigned short lds[32 * 36];
  const int bid = blockIdx.x;
  const int tk0 = (bid & 31) * 32;
  const int tn0 = (bid >> 5) * 32;
  const int t = threadIdx.x;
  {
    const int k  = t >> 3;
    const int nq = (t & 7) * 4;
    const int gi = (tk0 + k) * Ncols + tn0 + nq;
    const float4 wi = *(const float4*)(Win + gi);
    const float4 wo = *(const float4*)(Wout + gi);
    const float4 wr = *(const float4*)(Wroot + gi);
    lds[(nq + 0) * 36 + k] = f2bf(0.5f * (wi.x + wo.x) + wr.x);
    lds[(nq + 1) * 36 + k] = f2bf(0.5f * (wi.y + wo.y) + wr.y);
    lds[(nq + 2) * 36 + k] = f2bf(0.5f * (wi.z + wo.z) + wr.z);
    lds[(nq + 3) * 36 + k] = f2bf(0.5f * (wi.w + wo.w) + wr.w);
  }
  __syncthreads();
  {
    const int n  = t >> 3;
    const int k8 = (t & 7) * 4;
    const ushort4 v = *(const ushort4*)&lds[n * 36 + k8];
    *(ushort4*)(Wt + (size_t)(tn0 + n) * Kdim + tk0 + k8) = v;
  }
}

// ---------------------------------------------------------------------------
// Kernel 2: Y = X(fp32) @ Wt^T + bias, single fused pass (no X pre-cast).
// m97-style 2-barrier K-loop, but with the per-iteration FIXED cost halved
// (BK=64 -> 16 iters) and the per-FLOP LDS/issue cost halved (32x32x16 MFMA).
// Tile 128x128, 4 waves 2x2, wave-tile 64x64 = 2x2 MFMA tiles of 32x32
// (acc 4x16 fp32 = 64 VGPR). A: fp32 global -> register cvt -> bf16 ds_write.
// B: global_load_lds from L2-hot Wt, issued FIRST so its drain hides under
// the A path. LDS 16+16 KB single-buffered. XOR 16B-slot swizzle
// slot = chunk ^ (row&7) on both tiles (R3's scheme, 8-slot generalization).
// Grid 512, m-fast: n-peers (bid, bid+128,...) are == mod 8 -> same XCD.
// ---------------------------------------------------------------------------
__global__ __launch_bounds__(256, 2) void gemm_bk64(
    const float* __restrict__ X, const unsigned short* __restrict__ Wt,
    const float* __restrict__ b_in, const float* __restrict__ b_out,
    const float* __restrict__ b_root, float* __restrict__ Y)
{
  __shared__ __attribute__((aligned(16))) short As[128 * 64];   // 16 KB
  __shared__ __attribute__((aligned(16))) short Bs[128 * 64];   // 16 KB

  const int bid = blockIdx.x;
  const int m0 = (bid & 127) * 128;
  const int n0 = (bid >> 7) * 128;

  const int t    = threadIdx.x;
  const int lane = t & 63;
  const int w    = t >> 6;
  const int wm   = w >> 1;
  const int wn   = w & 1;
  const int l31  = lane & 31;
  const int khalf = lane >> 5;        // 0|1 : k-subgroup of the MFMA operand

  // --- A staging: thread -> row r = t>>1 (0..127), half h = t&1 (32 floats)
  const int r  = t >> 1;
  const int h  = t & 1;
  const float* xp = X + (size_t)(m0 + r) * Kdim + h * 32;
  // ds_write slots: chunk cc = h*4+c  ->  slot cc ^ (r&7)
  const int rsw = r & 7;
  int awr[4];
  #pragma unroll
  for (int c = 0; c < 4; ++c) awr[c] = r * 64 + (((h * 4 + c) ^ rsw) * 8);

  // --- B staging: wave w covers Wt rows w*32..+31, 4 insts x 8 rows
  const int rb = lane >> 3;           // 0..7
  const int sb = lane & 7;
  const int cb = sb ^ (rb & 7);
  const unsigned short* gB = Wt + (size_t)(n0 + w * 32 + rb) * Kdim + cb * 8;
  short* const lB = &Bs[(w * 32) * 64];
  const int rowK8 = 8 * Kdim;

  // --- fragment addressing: for (tile, ks): row ra, chunk cc = ks*2+khalf,
  //     slot = cc ^ (ra&7). (ra&7) == (l31&7) for all tiles.
  const int fsw = l31 & 7;
  const int arow0 = (wm * 64 + l31) * 64;
  const int brow0 = (wn * 64 + l31) * 64;

  f32x16 acc[2][2] = {};

  #pragma unroll 1
  for (int it = 0; it < 16; ++it) {
    const int kb = it * 64;

    // B DMA first (L2-hot; drains while A path runs)
    #pragma unroll
    for (int g = 0; g < 4; ++g)
      gl2lds16(gB + kb + (size_t)g * rowK8, lB + g * 8 * 64);

    // A: 8 float4 global loads -> cvt -> 4 ds_write_b128
    const float* xi = xp + kb;
    float4 v[8];
    #pragma unroll
    for (int c = 0; c < 8; ++c) v[c] = *(const float4*)(xi + c * 4);
    #pragma unroll
    for (int c = 0; c < 4; ++c) {
      uint4 pk;
      pk.x = f2bf2(v[2 * c].x,     v[2 * c].y);
      pk.y = f2bf2(v[2 * c].z,     v[2 * c].w);
      pk.z = f2bf2(v[2 * c + 1].x, v[2 * c + 1].y);
      pk.w = f2bf2(v[2 * c + 1].z, v[2 * c + 1].w);
      *(uint4*)&As[awr[c]] = pk;
    }

    __syncthreads();                  // tile staged

    #pragma unroll
    for (int ks = 0; ks < 4; ++ks) {
      const int slot = ((ks * 2 + khalf) ^ fsw) * 8;
      bf16x8 a0 = *(const bf16x8*)&As[arow0 +           slot];
      bf16x8 a1 = *(const bf16x8*)&As[arow0 + 32 * 64 + slot];
      bf16x8 b0 = *(const bf16x8*)&Bs[brow0 +           slot];
      bf16x8 b1 = *(const bf16x8*)&Bs[brow0 + 32 * 64 + slot];
      acc[0][0] = __builtin_amdgcn_mfma_f32_32x32x16_bf16(a0, b0, acc[0][0], 0, 0, 0);
      acc[0][1] = __builtin_amdgcn_mfma_f32_32x32x16_bf16(a0, b1, acc[0][1], 0, 0, 0);
      acc[1][0] = __builtin_amdgcn_mfma_f32_32x32x16_bf16(a1, b0, acc[1][0], 0, 0, 0);
      acc[1][1] = __builtin_amdgcn_mfma_f32_32x32x16_bf16(a1, b1, acc[1][1], 0, 0, 0);
    }

    __syncthreads();                  // frags consumed before overwrite
  }

  // epilogue: 32x32 C/D layout col = lane&31, row = (reg&3)+8*(reg>>2)+4*khalf
  #pragma unroll
  for (int nj = 0; nj < 2; ++nj) {
    const int gc = n0 + wn * 64 + nj * 32 + l31;
    const float bias = 0.5f * (b_in[gc] + b_out[gc]) + b_root[gc];
    #pragma unroll
    for (int mi = 0; mi < 2; ++mi) {
      const int gr0 = m0 + wm * 64 + mi * 32 + 4 * khalf;
      #pragma unroll
      for (int g = 0; g < 4; ++g) {          // reg>>2 groups
        float* yp = Y + (size_t)(gr0 + 8 * g) * Ncols + gc;
        #pragma unroll
        for (int q = 0; q < 4; ++q)          // reg&3
          yp[(size_t)q * Ncols] = acc[mi][nj][4 * g + q] + bias;
      }
    }
  }
}

// ---------------------------------------------------------------------------
extern "C" void kernel_launch(void* const* d_in, const int* in_sizes, int n_in,
                              void* d_out, int out_size, void* d_ws, size_t ws_size,
                              hipStream_t stream)
{
  const float* x      = (const float*)d_in[0];
  // d_in[1] = At : dead input (ChebConv K=1 -> no neighbor aggregation)
  const float* W_in   = (const float*)d_in[2];
  const float* b_in   = (const float*)d_in[3];
  const float* W_out  = (const float*)d_in[4];
  const float* b_out  = (const float*)d_in[5];
  const float* W_root = (const float*)d_in[6];
  const float* b_root = (const float*)d_in[7];
  float* y = (float*)d_out;

  unsigned short* Wt = (unsigned short*)d_ws;   // 512*1024 bf16 = 1 MiB

  combine_w<<<dim3(512), dim3(256), 0, stream>>>(W_in, W_out, W_root, Wt);
  gemm_bk64<<<dim3(512), dim3(256), 0, stream>>>(x, Wt, b_in, b_out, b_root, y);
}

// Round 7
// 158.144 us; speedup vs baseline: 1.0773x; 1.0773x over previous
//
#include <hip/hip_runtime.h>
#include <stdint.h>

static constexpr int Mrows = 16384;   // B*N = 64*256
static constexpr int Kdim  = 1024;    // L
static constexpr int Ncols = 512;     // OUT

typedef __attribute__((ext_vector_type(8))) short bf16x8;
typedef __attribute__((ext_vector_type(4))) float f32x4;

__device__ __forceinline__ unsigned short f2bf(float f) {
  unsigned u = __builtin_bit_cast(unsigned, f);
  u += 0x7FFFu + ((u >> 16) & 1u);          // RNE
  return (unsigned short)(u >> 16);
}
__device__ __forceinline__ unsigned f2bf2(float lo, float hi) {
  unsigned ul = __builtin_bit_cast(unsigned, lo);
  unsigned uh = __builtin_bit_cast(unsigned, hi);
  ul += 0x7FFFu + ((ul >> 16) & 1u);
  uh += 0x7FFFu + ((uh >> 16) & 1u);
  return (ul >> 16) | (uh & 0xFFFF0000u);
}

// async global->LDS, 16B per lane; LDS dest = wave-uniform base + lane*16
__device__ __forceinline__ void gl2lds16(const void* g, void* l) {
  __builtin_amdgcn_global_load_lds(
      (const __attribute__((address_space(1))) void*)g,
      (__attribute__((address_space(3))) void*)l, 16, 0, 0);
}

// ---------------------------------------------------------------------------
// prep: blocks [0,8192)   : Xbf = bf16(x)  (8 floats / thread, streaming)
//       blocks [8192,+512): Wt[n][k] = bf16(0.5*(W_in+W_out)+W_root)^T
// (Round-2 kernel, verbatim — measured fine.)
// ---------------------------------------------------------------------------
__global__ __launch_bounds__(256) void prep(
    const float* __restrict__ x,
    const float* __restrict__ Win, const float* __restrict__ Wout,
    const float* __restrict__ Wroot,
    unsigned short* __restrict__ Xbf, unsigned short* __restrict__ Wt)
{
  const int bid = blockIdx.x;
  const int t = threadIdx.x;
  if (bid < 8192) {
    const size_t base = ((size_t)bid * 256 + t) * 8;
    const float4 v0 = *(const float4*)(x + base);
    const float4 v1 = *(const float4*)(x + base + 4);
    uint4 p;
    p.x = f2bf2(v0.x, v0.y); p.y = f2bf2(v0.z, v0.w);
    p.z = f2bf2(v1.x, v1.y); p.w = f2bf2(v1.z, v1.w);
    *(uint4*)(Xbf + base) = p;
  } else {
    __shared__ unsigned short lds[32 * 36];
    const int b2 = bid - 8192;
    const int tk0 = (b2 & 31) * 32;
    const int tn0 = (b2 >> 5) * 32;
    {
      const int k  = t >> 3;
      const int nq = (t & 7) * 4;
      const int gi = (tk0 + k) * Ncols + tn0 + nq;
      const float4 wi = *(const float4*)(Win + gi);
      const float4 wo = *(const float4*)(Wout + gi);
      const float4 wr = *(const float4*)(Wroot + gi);
      lds[(nq + 0) * 36 + k] = f2bf(0.5f * (wi.x + wo.x) + wr.x);
      lds[(nq + 1) * 36 + k] = f2bf(0.5f * (wi.y + wo.y) + wr.y);
      lds[(nq + 2) * 36 + k] = f2bf(0.5f * (wi.z + wo.z) + wr.z);
      lds[(nq + 3) * 36 + k] = f2bf(0.5f * (wi.w + wo.w) + wr.w);
    }
    __syncthreads();
    {
      const int n  = t >> 3;
      const int k8 = (t & 7) * 4;
      const ushort4 v = *(const ushort4*)&lds[n * 36 + k8];
      *(ushort4*)(Wt + (size_t)(tn0 + n) * Kdim + tk0 + k8) = v;
    }
  }
}

// ---------------------------------------------------------------------------
// gemm: Y = Xbf @ Wt^T + bias.  Round-2's proven pure-DMA m97 structure
// (the only sub-40us variant), retiled 64x128 -> grid 1024 = 4 blocks/CU:
// double the independent barrier domains per CU (R4's occupancy lever) on
// top of the all-bf16 pure global_load_lds staging. 4 waves in 2x2, wave
// tile 32x64 (2x4 mfma_f32_16x16x32_bf16, acc=32 VGPR). LDS 4+8 KB single
// buffered, 2 barriers/iter. XOR 16B-slot swizzle slot=chunk^((row>>1)&3)
// on both tiles (measured 0 conflicts in R2/R3). m-fast block order: the 4
// n-peers of an X panel (bid+256k) are == mod 8 -> same XCD, and with 4
// blocks/CU the whole grid is co-resident -> X re-reads hit L2.
// ---------------------------------------------------------------------------
__global__ __launch_bounds__(256, 4) void gemm_bf16(
    const unsigned short* __restrict__ Xbf, const unsigned short* __restrict__ Wt,
    const float* __restrict__ b_in, const float* __restrict__ b_out,
    const float* __restrict__ b_root, float* __restrict__ Y)
{
  __shared__ __attribute__((aligned(16))) short As[64 * 32];    // 4 KB
  __shared__ __attribute__((aligned(16))) short Bs[128 * 32];   // 8 KB

  const int bid = blockIdx.x;
  const int m0 = (bid & 255) * 64;    // m fast
  const int n0 = (bid >> 8) * 128;

  const int t    = threadIdx.x;
  const int lane = t & 63;
  const int w    = t >> 6;
  const int wm   = w >> 1;
  const int wn   = w & 1;
  const int quad = lane >> 4;
  const int lm   = lane & 15;

  // --- A DMA: wave w stages rows w*16..+15 (one 1 KB inst)
  const int sr = lane >> 2;           // row within 16-row group
  const int ss = lane & 3;            // LDS 16B slot within row
  const unsigned short* gA =
      Xbf + (size_t)(m0 + w * 16 + sr) * Kdim + (ss ^ ((sr >> 1) & 3)) * 8;
  short* const lA = &As[(w * 16) * 32];

  // --- B DMA: wave w stages rows w*32..+31 (two 1 KB insts)
  const unsigned short* gB =
      Wt + (size_t)(n0 + w * 32 + sr) * Kdim + (ss ^ ((sr >> 1) & 3)) * 8;
  short* const lB0 = &Bs[(w * 32) * 32];
  short* const lB1 = &Bs[(w * 32 + 16) * 32];
  const int rowK16 = 16 * Kdim;

  // --- fragment offsets (shorts)
  const int slot = quad ^ ((lm >> 1) & 3);
  const int aoff = (wm * 32 + lm) * 32 + slot * 8;
  const int boff = (wn * 64 + lm) * 32 + slot * 8;

  f32x4 acc[2][4] = {};

  #pragma unroll 1
  for (int it = 0; it < 32; ++it) {
    const int kb = it * 32;
    gl2lds16(gA + kb,          lA);
    gl2lds16(gB + kb,          lB0);
    gl2lds16(gB + kb + rowK16, lB1);
    __syncthreads();                         // drain DMA: tile visible

    bf16x8 af[2], bfr[4];
    #pragma unroll
    for (int i = 0; i < 2; ++i) af[i]  = *(const bf16x8*)&As[aoff + i * 512];
    #pragma unroll
    for (int j = 0; j < 4; ++j) bfr[j] = *(const bf16x8*)&Bs[boff + j * 512];

    #pragma unroll
    for (int i = 0; i < 2; ++i)
      #pragma unroll
      for (int j = 0; j < 4; ++j)
        acc[i][j] = __builtin_amdgcn_mfma_f32_16x16x32_bf16(af[i], bfr[j], acc[i][j], 0, 0, 0);

    __syncthreads();                         // frags consumed before overwrite
  }

  // epilogue: D[row=(lane>>4)*4+reg][col=lane&15] per 16x16 tile; bias fused
  #pragma unroll
  for (int j = 0; j < 4; ++j) {
    const int gc = n0 + wn * 64 + j * 16 + lm;
    const float bias = 0.5f * (b_in[gc] + b_out[gc]) + b_root[gc];
    #pragma unroll
    for (int i = 0; i < 2; ++i) {
      const int gr = m0 + wm * 32 + i * 16 + quad * 4;
      float* yp = Y + (size_t)gr * Ncols + gc;
      #pragma unroll
      for (int r = 0; r < 4; ++r)
        yp[(size_t)r * Ncols] = acc[i][j][r] + bias;
    }
  }
}

// ---------------------------------------------------------------------------
extern "C" void kernel_launch(void* const* d_in, const int* in_sizes, int n_in,
                              void* d_out, int out_size, void* d_ws, size_t ws_size,
                              hipStream_t stream)
{
  const float* x      = (const float*)d_in[0];
  // d_in[1] = At : dead input (ChebConv K=1 -> no neighbor aggregation)
  const float* W_in   = (const float*)d_in[2];
  const float* b_in   = (const float*)d_in[3];
  const float* W_out  = (const float*)d_in[4];
  const float* b_out  = (const float*)d_in[5];
  const float* W_root = (const float*)d_in[6];
  const float* b_root = (const float*)d_in[7];
  float* y = (float*)d_out;

  unsigned short* Xbf = (unsigned short*)d_ws;                        // 32 MiB
  unsigned short* Wt  = (unsigned short*)d_ws + (size_t)Mrows * Kdim; // 1 MiB

  prep     <<<dim3(8192 + 512), dim3(256), 0, stream>>>(x, W_in, W_out, W_root, Xbf, Wt);
  gemm_bf16<<<dim3(1024),       dim3(256), 0, stream>>>(Xbf, Wt, b_in, b_out, b_root, y);
}